// Round 1
// baseline (334.085 us; speedup 1.0000x reference)
//
#include <hip/hip_runtime.h>

#define NUM_FACTORS 39
#define EMB_DIM 64
#define ROWS_PER_BLOCK 4   // 4 waves of 64 = 256 threads

__global__ __launch_bounds__(256) void fwfm_kernel(
    const int* __restrict__ x,            // (B, 39) int32
    const float* __restrict__ w0,         // (1,)
    const float* __restrict__ bias_table, // (1M, 1)
    const float* __restrict__ emb_table,  // (1M, 64)
    const float* __restrict__ W,          // (39, 39)
    float* __restrict__ out,              // (B,)
    int batch)
{
    const int lane = threadIdx.x & 63;
    const int wave = threadIdx.x >> 6;
    const int row  = blockIdx.x * ROWS_PER_BLOCK + wave;
    if (row >= batch) return;

    // Lane i (i<39) loads this row's i-th field index and its bias.
    int myidx = 0;
    float bpart = 0.0f;
    if (lane < NUM_FACTORS) {
        myidx = x[row * NUM_FACTORS + lane];
        bpart = bias_table[myidx];
    }

    // Gather embeddings: e[i] = emb_table[idx_i][lane].
    // __shfl(myidx, i) with constant i -> v_readlane -> SGPR row base;
    // the load is uniform-base + lane*4B: one coalesced 256B transaction per field.
    float e[NUM_FACTORS];
#pragma unroll
    for (int i = 0; i < NUM_FACTORS; ++i) {
        int ii = __shfl(myidx, i);
        e[i] = emb_table[(size_t)ii * EMB_DIM + lane];
    }

    // interactions partial for dim d = lane:
    // acc = sum_{i<j} W[i,j] * e_i[d] * e_j[d]
    // W[i*39+j] is wave-uniform, constant-indexed -> scalar loads (s_load),
    // FMAs take W as the single allowed SGPR operand. No LDS involved.
    float acc = 0.0f;
#pragma unroll
    for (int i = 0; i < NUM_FACTORS - 1; ++i) {
        float ti = 0.0f;
#pragma unroll
        for (int j = i + 1; j < NUM_FACTORS; ++j) {
            ti = fmaf(W[i * NUM_FACTORS + j], e[j], ti);
        }
        acc = fmaf(e[i], ti, acc);
    }

    // Sum over all 64 lanes: interaction partials (all lanes, dim=lane)
    // + bias partials (lanes < 39). One butterfly covers both.
    float total = acc + bpart;
#pragma unroll
    for (int off = 32; off > 0; off >>= 1)
        total += __shfl_xor(total, off);

    if (lane == 0) out[row] = w0[0] + total;
}

extern "C" void kernel_launch(void* const* d_in, const int* in_sizes, int n_in,
                              void* d_out, int out_size, void* d_ws, size_t ws_size,
                              hipStream_t stream) {
    const int*   x          = (const int*)d_in[0];
    const float* w0         = (const float*)d_in[1];
    const float* bias_table = (const float*)d_in[2];
    const float* emb_table  = (const float*)d_in[3];
    const float* W          = (const float*)d_in[4];
    float* out = (float*)d_out;

    const int batch = out_size;  // 16384
    const int grid = (batch + ROWS_PER_BLOCK - 1) / ROWS_PER_BLOCK;
    fwfm_kernel<<<grid, 256, 0, stream>>>(x, w0, bias_table, emb_table, W, out, batch);
}

// Round 2
// 333.778 us; speedup vs baseline: 1.0009x; 1.0009x over previous
//
#include <hip/hip_runtime.h>

#define NUM_FACTORS 39
#define EMB_DIM 64
#define ROWS_PER_BLOCK 4   // 4 waves of 64 = 256 threads

// (256, 8): cap VGPRs at 64 -> 8 waves/SIMD. Expected live set: e[39] + ~10
// temps (~50 VGPRs) since gather bases are scalarized via readlane.
__global__ __launch_bounds__(256, 8) void fwfm_kernel(
    const int* __restrict__ x,            // (B, 39) int32
    const float* __restrict__ w0,         // (1,)
    const float* __restrict__ bias_table, // (1M, 1)
    const float* __restrict__ emb_table,  // (1M, 64)
    const float* __restrict__ W,          // (39, 39)
    float* __restrict__ out,              // (B,)
    int batch)
{
    const int lane = threadIdx.x & 63;
    const int wave = threadIdx.x >> 6;
    const int row  = blockIdx.x * ROWS_PER_BLOCK + wave;
    if (row >= batch) return;

    // Lane i (i<39) loads this row's i-th field index and its bias.
    int myidx = 0;
    float bpart = 0.0f;
    if (lane < NUM_FACTORS) {
        myidx = x[row * NUM_FACTORS + lane];
        bpart = bias_table[myidx];
    }

    // Gather embeddings: e[i] = emb_table[idx_i][lane].
    // readlane(myidx, const) -> SGPR row index -> scalar base; the load is
    // global_load_dword v, v_off(lane*4), s[base]: one 256B coalesced
    // transaction per field, ONE shared address VGPR for all 39 gathers.
    float e[NUM_FACTORS];
#pragma unroll
    for (int i = 0; i < NUM_FACTORS; ++i) {
        unsigned ii = (unsigned)__builtin_amdgcn_readlane(myidx, i);
        e[i] = emb_table[(size_t)(ii * (unsigned)EMB_DIM) + (unsigned)lane];
    }

    // interactions partial for dim d = lane:
    // acc = sum_{i<j} W[i,j] * e_i[d] * e_j[d]
    // W[] accesses are wave-uniform + constant-indexed from a readonly
    // pointer -> scalar s_load batches; FMAs take W as the SGPR operand.
    float acc = 0.0f;
#pragma unroll
    for (int i = 0; i < NUM_FACTORS - 1; ++i) {
        float ti = 0.0f;
#pragma unroll
        for (int j = i + 1; j < NUM_FACTORS; ++j) {
            ti = fmaf(W[i * NUM_FACTORS + j], e[j], ti);
        }
        acc = fmaf(e[i], ti, acc);
    }

    // Sum over all 64 lanes: interaction partials (all lanes, dim=lane)
    // + bias partials (lanes < 39). One butterfly covers both.
    float total = acc + bpart;
#pragma unroll
    for (int off = 32; off > 0; off >>= 1)
        total += __shfl_xor(total, off);

    if (lane == 0) out[row] = w0[0] + total;
}

extern "C" void kernel_launch(void* const* d_in, const int* in_sizes, int n_in,
                              void* d_out, int out_size, void* d_ws, size_t ws_size,
                              hipStream_t stream) {
    const int*   x          = (const int*)d_in[0];
    const float* w0         = (const float*)d_in[1];
    const float* bias_table = (const float*)d_in[2];
    const float* emb_table  = (const float*)d_in[3];
    const float* W          = (const float*)d_in[4];
    float* out = (float*)d_out;

    const int batch = out_size;  // 16384
    const int grid = (batch + ROWS_PER_BLOCK - 1) / ROWS_PER_BLOCK;
    fwfm_kernel<<<grid, 256, 0, stream>>>(x, w0, bias_table, emb_table, W, out, batch);
}